// Round 4
// baseline (1315.777 us; speedup 1.0000x reference)
//
#include <hip/hip_runtime.h>
#include <hip/hip_bf16.h>

#define HID 72
#define EPSV 1e-5f
#define CAP 64   // per-node CSR slot capacity (Poisson(16), P(>64) ~ 1e-20; guarded anyway)
#define DP 76    // pitch: 16B aligned
#define NSH 32   // stat shadow copies (contention control for fused stats)
#define GF 256   // fill-role blocks in D2 (slot model: R~1024, co-work needs ~768)
#define GA 2048  // argmax-role blocks (grid-stride over nodes)

// ---------------------------------------------------------------- helpers
__device__ __forceinline__ float tanh_fast(float x) {
    float cx = fminf(fmaxf(x, -15.f), 15.f);
    float e = __expf(2.f * cx);
    return __fdividef(e - 1.f, e + 1.f);
}
__device__ __forceinline__ void fma4(float4& a, float w, const float4 v) {
    a.x += w * v.x; a.y += w * v.y; a.z += w * v.z; a.w += w * v.w;
}
__device__ __forceinline__ void add4(float4& a, const float4 v) {
    a.x += v.x; a.y += v.y; a.z += v.z; a.w += v.w;
}
__device__ __forceinline__ float inv_sqrt_deg(int d) {
    return (d > 0) ? rsqrtf((float)d) : 0.f;
}

// ---------------------------------------------------------------- D1: dense-x + dense-emb + zero(deg/shadows/bcnt)
__global__ __launch_bounds__(256) void k_d1(const float* __restrict__ x, const float* __restrict__ node_w,
                                            const float* __restrict__ node_b,
                                            const float* __restrict__ emb, const float* __restrict__ emb_w,
                                            const float* __restrict__ emb_b,
                                            float* __restrict__ t_buf, float* __restrict__ e_buf,
                                            int* __restrict__ deg, float* __restrict__ shadows,
                                            int* __restrict__ bcnt, int N, int B, int GD) {
    __shared__ float ws[HID][DP];
    int tid = threadIdx.x;
    int bid = blockIdx.x;
    if (bid >= 2 * GD) {
        int j = (bid - 2 * GD) * 256 + tid;
        if (j < N) deg[j] = 0;
        if (j < 3 * NSH * 2 * HID) shadows[j] = 0.f;
        if (j < B) bcnt[j] = 0;
        return;
    }
    const float* xin; const float* W; const float* bias; float* out;
    if (bid < GD) { xin = x;   W = node_w; bias = node_b; out = t_buf; }
    else          { xin = emb; W = emb_w;  bias = emb_b;  out = e_buf; bid -= GD; }
    int n0 = bid * 128;
    for (int i = tid; i < 64 * HID; i += 256) {
        int k = i / HID, f = i % HID;
        ws[f][k] = W[i];
    }
    __syncthreads();
    int tn = tid & 31;
    int tf = (tid >> 5) * 9;
    float acc[4][9];
    #pragma unroll
    for (int j = 0; j < 9; j++) {
        float b = bias[tf + j];
        acc[0][j] = b; acc[1][j] = b; acc[2][j] = b; acc[3][j] = b;
    }
    int g0 = n0 + tn;
    const float4* xp0 = (const float4*)(xin + (size_t)(g0      < N ? g0      : N - 1) * 64);
    const float4* xp1 = (const float4*)(xin + (size_t)(g0 + 32 < N ? g0 + 32 : N - 1) * 64);
    const float4* xp2 = (const float4*)(xin + (size_t)(g0 + 64 < N ? g0 + 64 : N - 1) * 64);
    const float4* xp3 = (const float4*)(xin + (size_t)(g0 + 96 < N ? g0 + 96 : N - 1) * 64);
    #pragma unroll 2
    for (int k4 = 0; k4 < 16; k4++) {
        float4 h0 = xp0[k4];
        float4 h1 = xp1[k4];
        float4 h2 = xp2[k4];
        float4 h3 = xp3[k4];
        int k = k4 * 4;
        #pragma unroll
        for (int j = 0; j < 9; j++) {
            float4 w = *(const float4*)&ws[tf + j][k];
            acc[0][j] += h0.x * w.x + h0.y * w.y + h0.z * w.z + h0.w * w.w;
            acc[1][j] += h1.x * w.x + h1.y * w.y + h1.z * w.z + h1.w * w.w;
            acc[2][j] += h2.x * w.x + h2.y * w.y + h2.z * w.z + h2.w * w.w;
            acc[3][j] += h3.x * w.x + h3.y * w.y + h3.z * w.z + h3.w * w.w;
        }
    }
    #pragma unroll
    for (int i = 0; i < 4; i++) {
        int gn = n0 + tn + 32 * i;
        if (gn >= N) continue;
        float* dst = out + (size_t)gn * HID + tf;
        #pragma unroll
        for (int j = 0; j < 9; j++) dst[j] = fmaxf(acc[i][j], 0.f);
    }
}

// ---------------------------------------------------------------- D2: fill + conv0(Wi-role, Wr-role) + argmax
// All roles <=22KB LDS so R ~ 4 blk/CU. conv0 split avoids in-place t race: Wi->hw, Wr->t2.
__global__ __launch_bounds__(256) void k_front2(const int* __restrict__ row, const int* __restrict__ col,
                                                int* __restrict__ deg, int* __restrict__ csr_r, int E,
                                                const float* __restrict__ t_buf,
                                                const float* __restrict__ wi0, const float* __restrict__ wr0,
                                                const float* __restrict__ cb0,
                                                float* __restrict__ hw, float* __restrict__ t2,
                                                const float* __restrict__ assign, int* __restrict__ batchv,
                                                int* __restrict__ bcnt, int N, int B, int GC) {
    __shared__ float ws[HID][DP];   // 21.9 KB
    int tid = threadIdx.x;
    int bid = blockIdx.x;

    if (bid < GF) {
        // ---- role A: CSR fill, 8 edges/thread/iter via int4, grid-stride
        int stride = GF * 256 * 8;
        for (int base = (bid * 256 + tid) * 8; base < E; base += stride) {
            #pragma unroll
            for (int h = 0; h < 2; h++) {
                int eb = base + h * 4;
                if (eb + 3 < E) {
                    int4 cc = *(const int4*)(col + eb);
                    int4 rr = *(const int4*)(row + eb);
                    int p0 = atomicAdd(&deg[cc.x], 1);
                    int p1 = atomicAdd(&deg[cc.y], 1);
                    int p2 = atomicAdd(&deg[cc.z], 1);
                    int p3 = atomicAdd(&deg[cc.w], 1);
                    if (p0 < CAP) csr_r[(size_t)cc.x * CAP + p0] = rr.x;
                    if (p1 < CAP) csr_r[(size_t)cc.y * CAP + p1] = rr.y;
                    if (p2 < CAP) csr_r[(size_t)cc.z * CAP + p2] = rr.z;
                    if (p3 < CAP) csr_r[(size_t)cc.w * CAP + p3] = rr.w;
                } else if (eb < E) {
                    int lim = (eb + 4 < E) ? eb + 4 : E;
                    for (int e = eb; e < lim; e++) {
                        int c = col[e];
                        int pos = atomicAdd(&deg[c], 1);
                        if (pos < CAP) csr_r[(size_t)c * CAP + pos] = row[e];
                    }
                }
            }
        }
        return;
    }
    bid -= GF;
    if (bid < 2 * GC) {
        // ---- roles B/C: conv0 half-matmuls over t (rows via L1/L2), 128-node tile, K=72
        const float* W; const float* bias; float* out;
        if (bid < GC) { W = wi0; bias = nullptr; out = hw; }
        else          { W = wr0; bias = cb0;     out = t2; bid -= GC; }
        int n0 = bid * 128;
        for (int i = tid; i < HID * HID; i += 256) {
            int k = i / HID, f = i % HID;
            ws[f][k] = W[i];
        }
        __syncthreads();
        int tn = tid & 31;
        int tf = (tid >> 5) * 9;
        float acc[4][9];
        #pragma unroll
        for (int j = 0; j < 9; j++) {
            float b = bias ? bias[tf + j] : 0.f;
            acc[0][j] = b; acc[1][j] = b; acc[2][j] = b; acc[3][j] = b;
        }
        int g0 = n0 + tn;
        const float* r0 = t_buf + (size_t)(g0      < N ? g0      : N - 1) * HID;
        const float* r1 = t_buf + (size_t)(g0 + 32 < N ? g0 + 32 : N - 1) * HID;
        const float* r2 = t_buf + (size_t)(g0 + 64 < N ? g0 + 64 : N - 1) * HID;
        const float* r3 = t_buf + (size_t)(g0 + 96 < N ? g0 + 96 : N - 1) * HID;
        #pragma unroll 2
        for (int k4 = 0; k4 < HID / 4; k4++) {
            int k = k4 * 4;
            float4 h0 = *(const float4*)(r0 + k);
            float4 h1 = *(const float4*)(r1 + k);
            float4 h2 = *(const float4*)(r2 + k);
            float4 h3 = *(const float4*)(r3 + k);
            #pragma unroll
            for (int j = 0; j < 9; j++) {
                float4 w = *(const float4*)&ws[tf + j][k];
                acc[0][j] += h0.x * w.x + h0.y * w.y + h0.z * w.z + h0.w * w.w;
                acc[1][j] += h1.x * w.x + h1.y * w.y + h1.z * w.z + h1.w * w.w;
                acc[2][j] += h2.x * w.x + h2.y * w.y + h2.z * w.z + h2.w * w.w;
                acc[3][j] += h3.x * w.x + h3.y * w.y + h3.z * w.z + h3.w * w.w;
            }
        }
        #pragma unroll
        for (int i = 0; i < 4; i++) {
            int gn = n0 + tn + 32 * i;
            if (gn >= N) continue;
            float* dst = out + (size_t)gn * HID + tf;
            #pragma unroll
            for (int j = 0; j < 9; j++) dst[j] = acc[i][j];
        }
        return;
    }
    bid -= 2 * GC;
    // ---- role D: argmax (wave per node, grid-stride)
    int wib = tid >> 6;
    int lane = tid & 63;
    int nq = B / 4;
    for (int n = bid * 4 + wib; n < N; n += GA * 4) {
        const float4* rp4 = (const float4*)(assign + (size_t)n * B);
        float best = -INFINITY;
        int bidx = 0x7fffffff;
        for (int q = lane; q < nq; q += 64) {
            float4 v = rp4[q];
            int j = q * 4;
            if (v.x > best) { best = v.x; bidx = j; }
            if (v.y > best) { best = v.y; bidx = j + 1; }
            if (v.z > best) { best = v.z; bidx = j + 2; }
            if (v.w > best) { best = v.w; bidx = j + 3; }
        }
        #pragma unroll
        for (int off = 32; off > 0; off >>= 1) {
            float ov = __shfl_down(best, off);
            int oi = __shfl_down(bidx, off);
            if (ov > best || (ov == best && oi < bidx)) { best = ov; bidx = oi; }
        }
        if (lane == 0) {
            batchv[n] = bidx;
            atomicAdd(&bcnt[bidx], 1);
        }
    }
}

// ---------------------------------------------------------------- gather: t[n] = relu(t2[n] + dis(n)*sum_j w_j*hw[r_j])
// SCALED=1: hw rows pre-scaled by dis(r) in conv epilogue -> inner loop is pure adds.
// Fused stats: per-block LDS sum/sumsq of outputs -> atomicAdd into shadow copy (blockIdx % NSH).
// Optional extra block (scanB>0): bucket-count exclusive scan.
template <int SCALED>
__global__ __launch_bounds__(256) void k_gather9(const float* __restrict__ hw, const int* __restrict__ deg,
                                                 const int* __restrict__ csr_r, const float* __restrict__ t2,
                                                 float* __restrict__ t, int N, float* __restrict__ shadow,
                                                 int scanB, const int* __restrict__ bcnt,
                                                 int* __restrict__ boffs, int* __restrict__ bcur) {
    if (scanB && blockIdx.x == gridDim.x - 1) {
        // wave-register scan of bucket counts (B <= 512: 64 lanes x 8 slots)
        int lane = threadIdx.x;
        if (lane < 64) {
            int c[8];
            int tot = 0;
            int base = lane * 8;
            #pragma unroll
            for (int j = 0; j < 8; j++) {
                int idx = base + j;
                c[j] = (idx < scanB) ? bcnt[idx] : 0;
                tot += c[j];
            }
            int v = tot;
            #pragma unroll
            for (int off = 1; off < 64; off <<= 1) {
                int u = __shfl_up(v, off);
                if (lane >= off) v += u;
            }
            int run = v - tot;
            #pragma unroll
            for (int j = 0; j < 8; j++) {
                int idx = base + j;
                if (idx < scanB) {
                    boffs[idx] = run;
                    bcur[idx] = run;
                    run += c[j];
                }
            }
        }
        return;
    }
    __shared__ float s1[HID], s2[HID];
    int tx = threadIdx.x;
    if (tx < HID) { s1[tx] = 0.f; s2[tx] = 0.f; }
    __syncthreads();
    int tid = blockIdx.x * blockDim.x + tx;
    int n = tid / 9;
    int s = tid - n * 9;
    if (n < N) {
        const float4* t2row = (const float4*)(t2 + (size_t)n * HID) + s * 2;
        float4 a0 = t2row[0], a1 = t2row[1];
        float4 b0 = make_float4(0.f, 0.f, 0.f, 0.f), b1 = b0;
        int dn = deg[n];
        int d = (dn > CAP) ? CAP : dn;
        float disc = inv_sqrt_deg(dn);
        const int* crow = csr_r + (size_t)n * CAP;
        const float4* hb = (const float4*)hw + s * 2;
        for (int j0 = 0; j0 < d; j0 += 4) {
            int4 rr = *(const int4*)(crow + j0);
            int rem = d - j0;
            {
                const float4* hp = hb + (size_t)rr.x * 18;
                if (SCALED) { add4(b0, hp[0]); add4(b1, hp[1]); }
                else { float w = inv_sqrt_deg(deg[rr.x]); fma4(b0, w, hp[0]); fma4(b1, w, hp[1]); }
            }
            if (rem > 1) {
                const float4* hp = hb + (size_t)rr.y * 18;
                if (SCALED) { add4(b0, hp[0]); add4(b1, hp[1]); }
                else { float w = inv_sqrt_deg(deg[rr.y]); fma4(b0, w, hp[0]); fma4(b1, w, hp[1]); }
            }
            if (rem > 2) {
                const float4* hp = hb + (size_t)rr.z * 18;
                if (SCALED) { add4(b0, hp[0]); add4(b1, hp[1]); }
                else { float w = inv_sqrt_deg(deg[rr.z]); fma4(b0, w, hp[0]); fma4(b1, w, hp[1]); }
            }
            if (rem > 3) {
                const float4* hp = hb + (size_t)rr.w * 18;
                if (SCALED) { add4(b0, hp[0]); add4(b1, hp[1]); }
                else { float w = inv_sqrt_deg(deg[rr.w]); fma4(b0, w, hp[0]); fma4(b1, w, hp[1]); }
            }
        }
        fma4(a0, disc, b0);
        fma4(a1, disc, b1);
        a0 = make_float4(fmaxf(a0.x, 0.f), fmaxf(a0.y, 0.f), fmaxf(a0.z, 0.f), fmaxf(a0.w, 0.f));
        a1 = make_float4(fmaxf(a1.x, 0.f), fmaxf(a1.y, 0.f), fmaxf(a1.z, 0.f), fmaxf(a1.w, 0.f));
        float4* trow = (float4*)(t + (size_t)n * HID) + s * 2;
        trow[0] = a0;
        trow[1] = a1;
        int f0 = s * 8;
        atomicAdd(&s1[f0 + 0], a0.x); atomicAdd(&s2[f0 + 0], a0.x * a0.x);
        atomicAdd(&s1[f0 + 1], a0.y); atomicAdd(&s2[f0 + 1], a0.y * a0.y);
        atomicAdd(&s1[f0 + 2], a0.z); atomicAdd(&s2[f0 + 2], a0.z * a0.z);
        atomicAdd(&s1[f0 + 3], a0.w); atomicAdd(&s2[f0 + 3], a0.w * a0.w);
        atomicAdd(&s1[f0 + 4], a1.x); atomicAdd(&s2[f0 + 4], a1.x * a1.x);
        atomicAdd(&s1[f0 + 5], a1.y); atomicAdd(&s2[f0 + 5], a1.y * a1.y);
        atomicAdd(&s1[f0 + 6], a1.z); atomicAdd(&s2[f0 + 6], a1.z * a1.z);
        atomicAdd(&s1[f0 + 7], a1.w); atomicAdd(&s2[f0 + 7], a1.w * a1.w);
    }
    __syncthreads();
    if (tx < HID) {
        float* shrow = shadow + (size_t)(blockIdx.x & (NSH - 1)) * (2 * HID);
        atomicAdd(&shrow[tx], s1[tx]);
        atomicAdd(&shrow[HID + tx], s2[tx]);
    }
}

// ---------------------------------------------------------------- tiled conv (BN from shadows): hn=BN(t); hw=dis*(hn@Wi); t2=hn@Wr+cb
// hw rows pre-scaled by dis(gn) so the next gather skips per-neighbor deg reads.
// Optional bfill role blocks [gcBlocks, grid).
#define CP 76
__global__ __launch_bounds__(256) void k_conv_t(const float* __restrict__ t, const float* __restrict__ shadow,
                                                const float* __restrict__ gamma, const float* __restrict__ beta,
                                                const float* __restrict__ wi, const float* __restrict__ wr,
                                                const float* __restrict__ cb, float* __restrict__ hw,
                                                float* __restrict__ t2, const int* __restrict__ deg,
                                                int N, float invN, int gcBlocks,
                                                const int* __restrict__ batchv, int* __restrict__ bcur,
                                                int* __restrict__ nlist) {
    __shared__ float hs[64][CP];        // 19.5 KB
    __shared__ float ws[2 * HID][CP];   // 43.8 KB
    __shared__ float bns[2 * HID];
    int tid = threadIdx.x;
    if ((int)blockIdx.x >= gcBlocks) {
        int n = ((int)blockIdx.x - gcBlocks) * 256 + tid;
        if (n < N) {
            int b = batchv[n];
            int pos = atomicAdd(&bcur[b], 1);
            nlist[pos] = n;
        }
        return;
    }
    // phase 1: BN stat reduction (32 shadows) + weight staging
    if (tid < 2 * HID) {
        float ssum = 0.f;
        #pragma unroll
        for (int c = 0; c < NSH; c++) ssum += shadow[c * 2 * HID + tid];
        bns[tid] = ssum;
    }
    for (int i = tid; i < HID * 2 * HID; i += 256) {
        int k = i / (2 * HID), f = i % (2 * HID);
        ws[f][k] = (f < HID) ? wi[k * HID + f] : wr[k * HID + (f - HID)];
    }
    __syncthreads();
    // phase 2: load + BN-normalize the 64-node tile
    int n0 = blockIdx.x * 64;
    for (int i = tid; i < 64 * HID; i += 256) {
        int n = i / HID, f = i % HID;
        int gn = n0 + n;
        float v = (gn < N) ? t[(size_t)gn * HID + f] : 0.f;
        float mu = bns[f] * invN;
        float var = bns[HID + f] * invN - mu * mu;
        v = (v - mu) * rsqrtf(var + EPSV) * gamma[f] + beta[f];
        hs[n][f] = v;
    }
    __syncthreads();
    int tn = tid & 15;
    int tf = (tid >> 4) * 9;
    float acc[4][9];
    #pragma unroll
    for (int j = 0; j < 9; j++) {
        float b = (tf >= HID) ? cb[tf - HID + j] : 0.f;
        acc[0][j] = b; acc[1][j] = b; acc[2][j] = b; acc[3][j] = b;
    }
    #pragma unroll 2
    for (int k4 = 0; k4 < HID / 4; k4++) {
        int k = k4 * 4;
        float4 h0 = *(const float4*)&hs[tn][k];
        float4 h1 = *(const float4*)&hs[tn + 16][k];
        float4 h2 = *(const float4*)&hs[tn + 32][k];
        float4 h3 = *(const float4*)&hs[tn + 48][k];
        #pragma unroll
        for (int j = 0; j < 9; j++) {
            float4 w = *(const float4*)&ws[tf + j][k];
            acc[0][j] += h0.x * w.x + h0.y * w.y + h0.z * w.z + h0.w * w.w;
            acc[1][j] += h1.x * w.x + h1.y * w.y + h1.z * w.z + h1.w * w.w;
            acc[2][j] += h2.x * w.x + h2.y * w.y + h2.z * w.z + h2.w * w.w;
            acc[3][j] += h3.x * w.x + h3.y * w.y + h3.z * w.z + h3.w * w.w;
        }
    }
    #pragma unroll
    for (int i = 0; i < 4; i++) {
        int gn = n0 + tn + 16 * i;
        if (gn >= N) continue;
        if (tf < HID) {
            float dsc = inv_sqrt_deg(deg[gn]);
            float* dst = hw + (size_t)gn * HID + tf;
            #pragma unroll
            for (int j = 0; j < 9; j++) dst[j] = acc[i][j] * dsc;
        } else {
            float* dst = t2 + (size_t)gn * HID + (tf - HID);
            #pragma unroll
            for (int j = 0; j < 9; j++) dst[j] = acc[i][j];
        }
    }
}

// ---------------------------------------------------------------- pooled features: xp[b] = [sum | max | mean] (BN from shadows)
__global__ __launch_bounds__(576) void k_poolB(const float* __restrict__ t2, const float* __restrict__ ebuf,
                                               const float* __restrict__ shadow2, const float* __restrict__ g2,
                                               const float* __restrict__ bt2, const int* __restrict__ boffs,
                                               const int* __restrict__ bcnt, const int* __restrict__ nlist,
                                               float* __restrict__ xp, float invN) {
    __shared__ float ls[4][2 * HID], lm[4][2 * HID];
    int b = blockIdx.x;
    int tid = threadIdx.x;
    int f = tid % (2 * HID);
    int ch = tid / (2 * HID);
    bool isH = f < HID;
    float a = 1.f, sh = 0.f;
    const float* src;
    if (isH) {
        float s1v = 0.f, s2v = 0.f;
        #pragma unroll
        for (int c = 0; c < NSH; c++) {
            s1v += shadow2[c * 2 * HID + f];
            s2v += shadow2[c * 2 * HID + HID + f];
        }
        float mu = s1v * invN;
        float var = s2v * invN - mu * mu;
        float inv = rsqrtf(var + EPSV);
        a = inv * g2[f];
        sh = bt2[f] - mu * a;
        src = t2 + f;
    } else {
        src = ebuf + (f - HID);
    }
    int s = boffs[b];
    int c = bcnt[b];
    int e = s + c;
    float sum = 0.f, mx = -INFINITY;
    for (int i = s + ch; i < e; i += 4) {
        float v = src[(size_t)nlist[i] * HID] * a + sh;
        sum += v;
        mx = fmaxf(mx, v);
    }
    ls[ch][f] = sum;
    lm[ch][f] = mx;
    __syncthreads();
    if (ch == 0) {
        float stot = ls[0][f] + ls[1][f] + ls[2][f] + ls[3][f];
        float mtot = fmaxf(fmaxf(lm[0][f], lm[1][f]), fmaxf(lm[2][f], lm[3][f]));
        float* xr = xp + (size_t)b * (6 * HID);
        xr[f] = stot;
        xr[2 * HID + f] = mtot;
        xr[4 * HID + f] = stot / fmaxf((float)c, 1.f);
    }
}

// ---------------------------------------------------------------- U = xp @ W1[:432] + b1 ; V = xp @ W1[432:]
__global__ __launch_bounds__(192) void k_uv(const float* __restrict__ xp, const float* __restrict__ w1,
                                            const float* __restrict__ b1, float* __restrict__ U,
                                            float* __restrict__ V) {
    int b = blockIdx.x;
    int t = threadIdx.x;
    if (t >= 2 * HID) return;
    int half = t / HID;
    int f = t % HID;
    const float* xr = xp + (size_t)b * (6 * HID);
    const float* wb = w1 + (size_t)half * (6 * HID) * HID + f;
    float acc = (half == 0) ? b1[f] : 0.f;
    #pragma unroll 4
    for (int k = 0; k < 6 * HID; k++) acc += xr[k] * wb[(size_t)k * HID];
    if (half == 0) U[(size_t)b * HID + f] = acc;
    else           V[(size_t)b * HID + f] = acc;
}

// ---------------------------------------------------------------- per pair-edge: out = tanh(U[a]+V[b]) . w2 + b2
__global__ __launch_bounds__(256) void k_edge(const int* __restrict__ pe, const float* __restrict__ U,
                                              const float* __restrict__ V, const float* __restrict__ w2,
                                              const float* __restrict__ b2, float* __restrict__ out, int EP) {
    int ep = blockIdx.x * blockDim.x + threadIdx.x;
    if (ep >= EP) return;
    int a = pe[ep];
    int b = pe[EP + ep];
    const float4* up = (const float4*)(U + (size_t)a * HID);
    const float4* vp = (const float4*)(V + (size_t)b * HID);
    float s = 0.f;
    #pragma unroll
    for (int q = 0; q < HID / 4; q++) {
        float4 u = up[q];
        float4 v = vp[q];
        s += tanh_fast(u.x + v.x) * w2[q * 4 + 0];
        s += tanh_fast(u.y + v.y) * w2[q * 4 + 1];
        s += tanh_fast(u.z + v.z) * w2[q * 4 + 2];
        s += tanh_fast(u.w + v.w) * w2[q * 4 + 3];
    }
    out[ep] = s + b2[0];
}

// ================================================================ host launch
extern "C" void kernel_launch(void* const* d_in, const int* in_sizes, int n_in,
                              void* d_out, int out_size, void* d_ws, size_t ws_size,
                              hipStream_t stream) {
    const float* x       = (const float*)d_in[0];
    const float* emb     = (const float*)d_in[1];
    const float* assign  = (const float*)d_in[2];
    const int*   ei      = (const int*)d_in[3];
    const int*   pe      = (const int*)d_in[4];
    const float* node_w  = (const float*)d_in[5];
    const float* node_b  = (const float*)d_in[6];
    const float* emb_w   = (const float*)d_in[7];
    const float* emb_b   = (const float*)d_in[8];
    const float* conv_wi = (const float*)d_in[9];
    const float* conv_wr = (const float*)d_in[10];
    const float* conv_b  = (const float*)d_in[11];
    const float* bn_g    = (const float*)d_in[12];
    const float* bn_b    = (const float*)d_in[13];
    const float* w1      = (const float*)d_in[14];
    const float* b1      = (const float*)d_in[15];
    const float* w2      = (const float*)d_in[16];
    const float* b2      = (const float*)d_in[17];

    int N = in_sizes[0] / 64;
    int B = in_sizes[2] / N;
    int E = in_sizes[3] / 2;
    int EP = in_sizes[4] / 2;
    float invN = 1.0f / (float)N;

    char* wp = (char*)d_ws;
    auto alloc = [&](size_t nbytes) -> void* {
        void* p = (void*)wp;
        wp += (nbytes + 255) & ~(size_t)255;
        return p;
    };
    float* t_buf  = (float*)alloc((size_t)N * HID * 4);
    float* t2     = (float*)alloc((size_t)N * HID * 4);
    float* hw     = (float*)alloc((size_t)N * HID * 4);
    float* e_buf  = (float*)alloc((size_t)N * HID * 4);
    int*   csr_r  = (int*)alloc((size_t)N * CAP * 4);
    int*   deg    = (int*)alloc((size_t)N * 4);
    int*   batchv = (int*)alloc((size_t)N * 4);
    int*   nlist  = (int*)alloc((size_t)N * 4);
    float* shadows= (float*)alloc((size_t)3 * NSH * 2 * HID * 4);
    int*   bcnt   = (int*)alloc((size_t)B * 4);
    int*   boffs  = (int*)alloc((size_t)B * 4);
    int*   bcur   = (int*)alloc((size_t)B * 4);
    float* xp     = (float*)alloc((size_t)B * 6 * HID * 4);
    float* Ub     = (float*)alloc((size_t)B * HID * 4);
    float* Vb     = (float*)alloc((size_t)B * HID * 4);

    const int* row = ei;
    const int* col = ei + E;

    int GD   = (N + 127) / 128;   // 128-node tiles (dense / conv0 halves)
    int GC64 = (N + 63) / 64;     // 64-node conv tiles
    int GZ   = (N + 255) / 256;   // zero/bfill blocks
    int GG   = (9 * N + 255) / 256;
    size_t shl = (size_t)NSH * 2 * HID;

    // D1: dense(x) + dense(emb) + zero-init
    k_d1<<<2 * GD + GZ, 256, 0, stream>>>(x, node_w, node_b, emb, emb_w, emb_b,
                                          t_buf, e_buf, deg, shadows, bcnt, N, B, GD);

    // D2: CSR fill + conv0 (Wi->hw, Wr->t2) + argmax
    k_front2<<<GF + 2 * GD + GA, 256, 0, stream>>>(row, col, deg, csr_r, E,
                                                   t_buf, conv_wi, conv_wr, conv_b, hw, t2,
                                                   assign, batchv, bcnt, N, B, GD);

    // layer 0: gather (UNSCALED: hw not deg-scaled) + fused stats + bucket scan
    k_gather9<0><<<GG + 1, 256, 0, stream>>>(hw, deg, csr_r, t2, t_buf, N, shadows,
                                             B, bcnt, boffs, bcur);

    // layer 1: conv (BN from l0 shadows, hw pre-scaled) + bfill role
    k_conv_t<<<GC64 + GZ, 256, 0, stream>>>(t_buf, shadows, bn_g, bn_b,
                                            conv_wi + (size_t)HID * HID, conv_wr + (size_t)HID * HID,
                                            conv_b + HID, hw, t2, deg, N, invN, GC64,
                                            batchv, bcur, nlist);
    k_gather9<1><<<GG, 256, 0, stream>>>(hw, deg, csr_r, t2, t_buf, N, shadows + shl,
                                         0, nullptr, nullptr, nullptr);

    // layer 2: conv (BN from l1 shadows), gather
    k_conv_t<<<GC64, 256, 0, stream>>>(t_buf, shadows + shl, bn_g + HID, bn_b + HID,
                                       conv_wi + (size_t)2 * HID * HID, conv_wr + (size_t)2 * HID * HID,
                                       conv_b + 2 * HID, hw, t2, deg, N, invN, GC64,
                                       nullptr, nullptr, nullptr);
    k_gather9<1><<<GG, 256, 0, stream>>>(hw, deg, csr_r, t2, t_buf, N, shadows + 2 * shl,
                                         0, nullptr, nullptr, nullptr);

    // pooling + MLP (pool BN from l2 shadows)
    k_poolB<<<B, 576, 0, stream>>>(t_buf, e_buf, shadows + 2 * shl,
                                   bn_g + 2 * HID, bn_b + 2 * HID,
                                   boffs, bcnt, nlist, xp, invN);
    k_uv<<<B, 192, 0, stream>>>(xp, w1, b1, Ub, Vb);
    k_edge<<<(EP + 255) / 256, 256, 0, stream>>>(pe, Ub, Vb, w2, b2, (float*)d_out, EP);
}

// Round 6
// 1177.469 us; speedup vs baseline: 1.1175x; 1.1175x over previous
//
#include <hip/hip_runtime.h>
#include <hip/hip_bf16.h>

#define HID 72
#define EPSV 1e-5f
#define CAP 64   // per-node CSR slot capacity (Poisson(16), P(>64) ~ 1e-20; guarded anyway)
#define DP 76    // pitch: 16B aligned
#define GF 256   // fill-role blocks in D2 (slot model: R~1024, co-work needs ~768)
#define GA 2048  // argmax-role blocks (grid-stride over nodes)

// ---------------------------------------------------------------- helpers
__device__ __forceinline__ float tanh_fast(float x) {
    float cx = fminf(fmaxf(x, -15.f), 15.f);
    float e = __expf(2.f * cx);
    return __fdividef(e - 1.f, e + 1.f);
}
__device__ __forceinline__ void fma4(float4& a, float w, const float4 v) {
    a.x += w * v.x; a.y += w * v.y; a.z += w * v.z; a.w += w * v.w;
}
__device__ __forceinline__ void add4(float4& a, const float4 v) {
    a.x += v.x; a.y += v.y; a.z += v.z; a.w += v.w;
}
__device__ __forceinline__ float inv_sqrt_deg(int d) {
    return (d > 0) ? rsqrtf((float)d) : 0.f;
}

// ---------------------------------------------------------------- D1: dense-x + dense-emb + zero(deg/stats/bcnt)
__global__ __launch_bounds__(256) void k_d1(const float* __restrict__ x, const float* __restrict__ node_w,
                                            const float* __restrict__ node_b,
                                            const float* __restrict__ emb, const float* __restrict__ emb_w,
                                            const float* __restrict__ emb_b,
                                            float* __restrict__ t_buf, float* __restrict__ e_buf,
                                            int* __restrict__ deg, float* __restrict__ stats,
                                            int* __restrict__ bcnt, int N, int B, int GD) {
    __shared__ float ws[HID][DP];
    int tid = threadIdx.x;
    int bid = blockIdx.x;
    if (bid >= 2 * GD) {
        int j = (bid - 2 * GD) * 256 + tid;
        if (j < N) deg[j] = 0;
        if (j < 3 * 2 * HID) stats[j] = 0.f;
        if (j < B) bcnt[j] = 0;
        return;
    }
    const float* xin; const float* W; const float* bias; float* out;
    if (bid < GD) { xin = x;   W = node_w; bias = node_b; out = t_buf; }
    else          { xin = emb; W = emb_w;  bias = emb_b;  out = e_buf; bid -= GD; }
    int n0 = bid * 128;
    for (int i = tid; i < 64 * HID; i += 256) {
        int k = i / HID, f = i % HID;
        ws[f][k] = W[i];
    }
    __syncthreads();
    int tn = tid & 31;
    int tf = (tid >> 5) * 9;
    float acc[4][9];
    #pragma unroll
    for (int j = 0; j < 9; j++) {
        float b = bias[tf + j];
        acc[0][j] = b; acc[1][j] = b; acc[2][j] = b; acc[3][j] = b;
    }
    int g0 = n0 + tn;
    const float4* xp0 = (const float4*)(xin + (size_t)(g0      < N ? g0      : N - 1) * 64);
    const float4* xp1 = (const float4*)(xin + (size_t)(g0 + 32 < N ? g0 + 32 : N - 1) * 64);
    const float4* xp2 = (const float4*)(xin + (size_t)(g0 + 64 < N ? g0 + 64 : N - 1) * 64);
    const float4* xp3 = (const float4*)(xin + (size_t)(g0 + 96 < N ? g0 + 96 : N - 1) * 64);
    #pragma unroll 2
    for (int k4 = 0; k4 < 16; k4++) {
        float4 h0 = xp0[k4];
        float4 h1 = xp1[k4];
        float4 h2 = xp2[k4];
        float4 h3 = xp3[k4];
        int k = k4 * 4;
        #pragma unroll
        for (int j = 0; j < 9; j++) {
            float4 w = *(const float4*)&ws[tf + j][k];
            acc[0][j] += h0.x * w.x + h0.y * w.y + h0.z * w.z + h0.w * w.w;
            acc[1][j] += h1.x * w.x + h1.y * w.y + h1.z * w.z + h1.w * w.w;
            acc[2][j] += h2.x * w.x + h2.y * w.y + h2.z * w.z + h2.w * w.w;
            acc[3][j] += h3.x * w.x + h3.y * w.y + h3.z * w.z + h3.w * w.w;
        }
    }
    #pragma unroll
    for (int i = 0; i < 4; i++) {
        int gn = n0 + tn + 32 * i;
        if (gn >= N) continue;
        float* dst = out + (size_t)gn * HID + tf;
        #pragma unroll
        for (int j = 0; j < 9; j++) dst[j] = fmaxf(acc[i][j], 0.f);
    }
}

// ---------------------------------------------------------------- D2: fill + conv0(Wi-role, Wr-role) + argmax
// All roles <=22KB LDS so R ~ 4 blk/CU. conv0 split avoids in-place t race: Wi->hw, Wr->t2.
__global__ __launch_bounds__(256) void k_front2(const int* __restrict__ row, const int* __restrict__ col,
                                                int* __restrict__ deg, int* __restrict__ csr_r, int E,
                                                const float* __restrict__ t_buf,
                                                const float* __restrict__ wi0, const float* __restrict__ wr0,
                                                const float* __restrict__ cb0,
                                                float* __restrict__ hw, float* __restrict__ t2,
                                                const float* __restrict__ assign, int* __restrict__ batchv,
                                                int* __restrict__ bcnt, int N, int B, int GC) {
    __shared__ float ws[HID][DP];   // 21.9 KB
    int tid = threadIdx.x;
    int bid = blockIdx.x;

    if (bid < GF) {
        // ---- role A: CSR fill, 8 edges/thread/iter via int4, grid-stride
        int stride = GF * 256 * 8;
        for (int base = (bid * 256 + tid) * 8; base < E; base += stride) {
            #pragma unroll
            for (int h = 0; h < 2; h++) {
                int eb = base + h * 4;
                if (eb + 3 < E) {
                    int4 cc = *(const int4*)(col + eb);
                    int4 rr = *(const int4*)(row + eb);
                    int p0 = atomicAdd(&deg[cc.x], 1);
                    int p1 = atomicAdd(&deg[cc.y], 1);
                    int p2 = atomicAdd(&deg[cc.z], 1);
                    int p3 = atomicAdd(&deg[cc.w], 1);
                    if (p0 < CAP) csr_r[(size_t)cc.x * CAP + p0] = rr.x;
                    if (p1 < CAP) csr_r[(size_t)cc.y * CAP + p1] = rr.y;
                    if (p2 < CAP) csr_r[(size_t)cc.z * CAP + p2] = rr.z;
                    if (p3 < CAP) csr_r[(size_t)cc.w * CAP + p3] = rr.w;
                } else if (eb < E) {
                    int lim = (eb + 4 < E) ? eb + 4 : E;
                    for (int e = eb; e < lim; e++) {
                        int c = col[e];
                        int pos = atomicAdd(&deg[c], 1);
                        if (pos < CAP) csr_r[(size_t)c * CAP + pos] = row[e];
                    }
                }
            }
        }
        return;
    }
    bid -= GF;
    if (bid < 2 * GC) {
        // ---- roles B/C: conv0 half-matmuls over t (rows via L1/L2), 128-node tile, K=72
        const float* W; const float* bias; float* out;
        if (bid < GC) { W = wi0; bias = nullptr; out = hw; }
        else          { W = wr0; bias = cb0;     out = t2; bid -= GC; }
        int n0 = bid * 128;
        for (int i = tid; i < HID * HID; i += 256) {
            int k = i / HID, f = i % HID;
            ws[f][k] = W[i];
        }
        __syncthreads();
        int tn = tid & 31;
        int tf = (tid >> 5) * 9;
        float acc[4][9];
        #pragma unroll
        for (int j = 0; j < 9; j++) {
            float b = bias ? bias[tf + j] : 0.f;
            acc[0][j] = b; acc[1][j] = b; acc[2][j] = b; acc[3][j] = b;
        }
        int g0 = n0 + tn;
        const float* r0 = t_buf + (size_t)(g0      < N ? g0      : N - 1) * HID;
        const float* r1 = t_buf + (size_t)(g0 + 32 < N ? g0 + 32 : N - 1) * HID;
        const float* r2 = t_buf + (size_t)(g0 + 64 < N ? g0 + 64 : N - 1) * HID;
        const float* r3 = t_buf + (size_t)(g0 + 96 < N ? g0 + 96 : N - 1) * HID;
        #pragma unroll 2
        for (int k4 = 0; k4 < HID / 4; k4++) {
            int k = k4 * 4;
            float4 h0 = *(const float4*)(r0 + k);
            float4 h1 = *(const float4*)(r1 + k);
            float4 h2 = *(const float4*)(r2 + k);
            float4 h3 = *(const float4*)(r3 + k);
            #pragma unroll
            for (int j = 0; j < 9; j++) {
                float4 w = *(const float4*)&ws[tf + j][k];
                acc[0][j] += h0.x * w.x + h0.y * w.y + h0.z * w.z + h0.w * w.w;
                acc[1][j] += h1.x * w.x + h1.y * w.y + h1.z * w.z + h1.w * w.w;
                acc[2][j] += h2.x * w.x + h2.y * w.y + h2.z * w.z + h2.w * w.w;
                acc[3][j] += h3.x * w.x + h3.y * w.y + h3.z * w.z + h3.w * w.w;
            }
        }
        #pragma unroll
        for (int i = 0; i < 4; i++) {
            int gn = n0 + tn + 32 * i;
            if (gn >= N) continue;
            float* dst = out + (size_t)gn * HID + tf;
            #pragma unroll
            for (int j = 0; j < 9; j++) dst[j] = acc[i][j];
        }
        return;
    }
    bid -= 2 * GC;
    // ---- role D: argmax (wave per node, grid-stride)
    int wib = tid >> 6;
    int lane = tid & 63;
    int nq = B / 4;
    for (int n = bid * 4 + wib; n < N; n += GA * 4) {
        const float4* rp4 = (const float4*)(assign + (size_t)n * B);
        float best = -INFINITY;
        int bidx = 0x7fffffff;
        for (int q = lane; q < nq; q += 64) {
            float4 v = rp4[q];
            int j = q * 4;
            if (v.x > best) { best = v.x; bidx = j; }
            if (v.y > best) { best = v.y; bidx = j + 1; }
            if (v.z > best) { best = v.z; bidx = j + 2; }
            if (v.w > best) { best = v.w; bidx = j + 3; }
        }
        #pragma unroll
        for (int off = 32; off > 0; off >>= 1) {
            float ov = __shfl_down(best, off);
            int oi = __shfl_down(bidx, off);
            if (ov > best || (ov == best && oi < bidx)) { best = ov; bidx = oi; }
        }
        if (lane == 0) {
            batchv[n] = bidx;
            atomicAdd(&bcnt[bidx], 1);
        }
    }
}

// ---------------------------------------------------------------- gather (18 threads/node, 1 float4 each):
// t[n] = relu(t2[n] + dis(n)*sum_j w_j*hw[r_j]).  SCALED=1: hw rows pre-scaled by dis(r).
// No barriers -> waves retire independently (latency-bound; barrier coupling cost ~60us/launch, R4).
// Optional extra block (scanB>0): bucket-count exclusive scan.
template <int SCALED>
__global__ __launch_bounds__(256) void k_gather18(const float* __restrict__ hw, const int* __restrict__ deg,
                                                  const int* __restrict__ csr_r, const float* __restrict__ t2,
                                                  float* __restrict__ t, int N,
                                                  int scanB, const int* __restrict__ bcnt,
                                                  int* __restrict__ boffs, int* __restrict__ bcur) {
    if (scanB && blockIdx.x == gridDim.x - 1) {
        // wave-register scan of bucket counts (B <= 512: 64 lanes x 8 slots)
        int lane = threadIdx.x;
        if (lane < 64) {
            int c[8];
            int tot = 0;
            int base = lane * 8;
            #pragma unroll
            for (int j = 0; j < 8; j++) {
                int idx = base + j;
                c[j] = (idx < scanB) ? bcnt[idx] : 0;
                tot += c[j];
            }
            int v = tot;
            #pragma unroll
            for (int off = 1; off < 64; off <<= 1) {
                int u = __shfl_up(v, off);
                if (lane >= off) v += u;
            }
            int run = v - tot;
            #pragma unroll
            for (int j = 0; j < 8; j++) {
                int idx = base + j;
                if (idx < scanB) {
                    boffs[idx] = run;
                    bcur[idx] = run;
                    run += c[j];
                }
            }
        }
        return;
    }
    int tid = blockIdx.x * blockDim.x + threadIdx.x;
    int n = tid / 18;
    int s = tid - n * 18;
    if (n >= N) return;
    float4 a0 = *((const float4*)(t2 + (size_t)n * HID) + s);
    float4 b0 = make_float4(0.f, 0.f, 0.f, 0.f);
    int dn = deg[n];
    int d = (dn > CAP) ? CAP : dn;
    float disc = inv_sqrt_deg(dn);
    const int* crow = csr_r + (size_t)n * CAP;
    const float4* hb = (const float4*)hw + s;
    for (int j0 = 0; j0 < d; j0 += 4) {
        int4 rr = *(const int4*)(crow + j0);
        int rem = d - j0;
        {
            float4 hv = hb[(size_t)rr.x * 18];
            if (SCALED) add4(b0, hv); else fma4(b0, inv_sqrt_deg(deg[rr.x]), hv);
        }
        if (rem > 1) {
            float4 hv = hb[(size_t)rr.y * 18];
            if (SCALED) add4(b0, hv); else fma4(b0, inv_sqrt_deg(deg[rr.y]), hv);
        }
        if (rem > 2) {
            float4 hv = hb[(size_t)rr.z * 18];
            if (SCALED) add4(b0, hv); else fma4(b0, inv_sqrt_deg(deg[rr.z]), hv);
        }
        if (rem > 3) {
            float4 hv = hb[(size_t)rr.w * 18];
            if (SCALED) add4(b0, hv); else fma4(b0, inv_sqrt_deg(deg[rr.w]), hv);
        }
    }
    fma4(a0, disc, b0);
    *((float4*)(t + (size_t)n * HID) + s) =
        make_float4(fmaxf(a0.x, 0.f), fmaxf(a0.y, 0.f), fmaxf(a0.z, 0.f), fmaxf(a0.w, 0.f));
}

// ---------------------------------------------------------------- per-feature sum & sumsq (column-stable grid stride)
// REQUIRES grid*block*4 % HID == 0 (288*256*4 / 72 = 4096 exactly)
__global__ __launch_bounds__(256) void k_stats(const float* __restrict__ t, float* __restrict__ st, int total4) {
    __shared__ float s1[HID], s2[HID];
    int tx = threadIdx.x;
    if (tx < HID) s1[tx] = 0.f;
    else if (tx < 2 * HID) s2[tx - HID] = 0.f;
    __syncthreads();
    int stride = gridDim.x * blockDim.x;
    int i0 = blockIdx.x * blockDim.x + tx;
    int f0 = (i0 * 4) % HID;
    float a0 = 0, a1 = 0, a2 = 0, a3 = 0, q0 = 0, q1 = 0, q2 = 0, q3 = 0;
    const float4* tp = (const float4*)t;
    for (int i = i0; i < total4; i += stride) {
        float4 v = tp[i];
        a0 += v.x; q0 += v.x * v.x;
        a1 += v.y; q1 += v.y * v.y;
        a2 += v.z; q2 += v.z * v.z;
        a3 += v.w; q3 += v.w * v.w;
    }
    atomicAdd(&s1[f0 + 0], a0); atomicAdd(&s2[f0 + 0], q0);
    atomicAdd(&s1[f0 + 1], a1); atomicAdd(&s2[f0 + 1], q1);
    atomicAdd(&s1[f0 + 2], a2); atomicAdd(&s2[f0 + 2], q2);
    atomicAdd(&s1[f0 + 3], a3); atomicAdd(&s2[f0 + 3], q3);
    __syncthreads();
    if (tx < HID) {
        atomicAdd(&st[tx], s1[tx]);
        atomicAdd(&st[HID + tx], s2[tx]);
    }
}

// ---------------------------------------------------------------- split BN-conv: two 128-node-tile roles (22.5KB LDS, 4 blk/CU)
// role Wi (blocks [0,GD)):   hw = dis * (BN(t) @ Wi)
// role Wr (blocks [GD,2GD)): t2 = BN(t) @ Wr + cb
// BN applied on-the-fly via per-feature (a,sh) LDS table. Optional bfill role [2GD, grid).
__global__ __launch_bounds__(256) void k_conv_s(const float* __restrict__ t, const float* __restrict__ stats,
                                                const float* __restrict__ gamma, const float* __restrict__ beta,
                                                const float* __restrict__ wi, const float* __restrict__ wr,
                                                const float* __restrict__ cb, float* __restrict__ hw,
                                                float* __restrict__ t2, const int* __restrict__ deg,
                                                int N, float invN, int GD,
                                                const int* __restrict__ batchv, int* __restrict__ bcur,
                                                int* __restrict__ nlist) {
    __shared__ float ws[HID][DP];
    __shared__ __align__(16) float bna[HID];
    __shared__ __align__(16) float bnsh[HID];
    int tid = threadIdx.x;
    int bid = blockIdx.x;
    if (bid >= 2 * GD) {
        int n = (bid - 2 * GD) * 256 + tid;
        if (n < N) {
            int b = batchv[n];
            int pos = atomicAdd(&bcur[b], 1);
            nlist[pos] = n;
        }
        return;
    }
    const float* W; bool isWi;
    if (bid < GD) { W = wi; isWi = true; }
    else          { W = wr; isWi = false; bid -= GD; }
    if (tid < HID) {
        float mu = stats[tid] * invN;
        float var = stats[HID + tid] * invN - mu * mu;
        float a = rsqrtf(var + EPSV) * gamma[tid];
        bna[tid] = a;
        bnsh[tid] = beta[tid] - mu * a;
    }
    for (int i = tid; i < HID * HID; i += 256) {
        int k = i / HID, f = i % HID;
        ws[f][k] = W[i];
    }
    __syncthreads();
    int n0 = bid * 128;
    int tn = tid & 31;
    int tf = (tid >> 5) * 9;
    float acc[4][9];
    #pragma unroll
    for (int j = 0; j < 9; j++) {
        float b = isWi ? 0.f : cb[tf + j];
        acc[0][j] = b; acc[1][j] = b; acc[2][j] = b; acc[3][j] = b;
    }
    int g0 = n0 + tn;
    const float* r0 = t + (size_t)(g0      < N ? g0      : N - 1) * HID;
    const float* r1 = t + (size_t)(g0 + 32 < N ? g0 + 32 : N - 1) * HID;
    const float* r2 = t + (size_t)(g0 + 64 < N ? g0 + 64 : N - 1) * HID;
    const float* r3 = t + (size_t)(g0 + 96 < N ? g0 + 96 : N - 1) * HID;
    #pragma unroll 2
    for (int k4 = 0; k4 < HID / 4; k4++) {
        int k = k4 * 4;
        float4 av = *(const float4*)&bna[k];
        float4 sv = *(const float4*)&bnsh[k];
        float4 h0 = *(const float4*)(r0 + k);
        float4 h1 = *(const float4*)(r1 + k);
        float4 h2 = *(const float4*)(r2 + k);
        float4 h3 = *(const float4*)(r3 + k);
        h0.x = h0.x * av.x + sv.x; h0.y = h0.y * av.y + sv.y; h0.z = h0.z * av.z + sv.z; h0.w = h0.w * av.w + sv.w;
        h1.x = h1.x * av.x + sv.x; h1.y = h1.y * av.y + sv.y; h1.z = h1.z * av.z + sv.z; h1.w = h1.w * av.w + sv.w;
        h2.x = h2.x * av.x + sv.x; h2.y = h2.y * av.y + sv.y; h2.z = h2.z * av.z + sv.z; h2.w = h2.w * av.w + sv.w;
        h3.x = h3.x * av.x + sv.x; h3.y = h3.y * av.y + sv.y; h3.z = h3.z * av.z + sv.z; h3.w = h3.w * av.w + sv.w;
        #pragma unroll
        for (int j = 0; j < 9; j++) {
            float4 w = *(const float4*)&ws[tf + j][k];
            acc[0][j] += h0.x * w.x + h0.y * w.y + h0.z * w.z + h0.w * w.w;
            acc[1][j] += h1.x * w.x + h1.y * w.y + h1.z * w.z + h1.w * w.w;
            acc[2][j] += h2.x * w.x + h2.y * w.y + h2.z * w.z + h2.w * w.w;
            acc[3][j] += h3.x * w.x + h3.y * w.y + h3.z * w.z + h3.w * w.w;
        }
    }
    #pragma unroll
    for (int i = 0; i < 4; i++) {
        int gn = n0 + tn + 32 * i;
        if (gn >= N) continue;
        if (isWi) {
            float dsc = inv_sqrt_deg(deg[gn]);
            float* dst = hw + (size_t)gn * HID + tf;
            #pragma unroll
            for (int j = 0; j < 9; j++) dst[j] = acc[i][j] * dsc;
        } else {
            float* dst = t2 + (size_t)gn * HID + tf;
            #pragma unroll
            for (int j = 0; j < 9; j++) dst[j] = acc[i][j];
        }
    }
}

// ---------------------------------------------------------------- pooled features: xp[b] = [sum | max | mean]
__global__ __launch_bounds__(576) void k_poolB(const float* __restrict__ t2, const float* __restrict__ ebuf,
                                               const float* __restrict__ stats2, const float* __restrict__ g2,
                                               const float* __restrict__ bt2, const int* __restrict__ boffs,
                                               const int* __restrict__ bcnt, const int* __restrict__ nlist,
                                               float* __restrict__ xp, float invN) {
    __shared__ float ls[4][2 * HID], lm[4][2 * HID];
    int b = blockIdx.x;
    int tid = threadIdx.x;
    int f = tid % (2 * HID);
    int ch = tid / (2 * HID);
    bool isH = f < HID;
    float a = 1.f, sh = 0.f;
    const float* src;
    if (isH) {
        float s1v = stats2[f], s2v = stats2[HID + f];
        float mu = s1v * invN;
        float var = s2v * invN - mu * mu;
        float inv = rsqrtf(var + EPSV);
        a = inv * g2[f];
        sh = bt2[f] - mu * a;
        src = t2 + f;
    } else {
        src = ebuf + (f - HID);
    }
    int s = boffs[b];
    int c = bcnt[b];
    int e = s + c;
    float sum = 0.f, mx = -INFINITY;
    for (int i = s + ch; i < e; i += 4) {
        float v = src[(size_t)nlist[i] * HID] * a + sh;
        sum += v;
        mx = fmaxf(mx, v);
    }
    ls[ch][f] = sum;
    lm[ch][f] = mx;
    __syncthreads();
    if (ch == 0) {
        float stot = ls[0][f] + ls[1][f] + ls[2][f] + ls[3][f];
        float mtot = fmaxf(fmaxf(lm[0][f], lm[1][f]), fmaxf(lm[2][f], lm[3][f]));
        float* xr = xp + (size_t)b * (6 * HID);
        xr[f] = stot;
        xr[2 * HID + f] = mtot;
        xr[4 * HID + f] = stot / fmaxf((float)c, 1.f);
    }
}

// ---------------------------------------------------------------- U = xp @ W1[:432] + b1 ; V = xp @ W1[432:]
__global__ __launch_bounds__(192) void k_uv(const float* __restrict__ xp, const float* __restrict__ w1,
                                            const float* __restrict__ b1, float* __restrict__ U,
                                            float* __restrict__ V) {
    int b = blockIdx.x;
    int t = threadIdx.x;
    if (t >= 2 * HID) return;
    int half = t / HID;
    int f = t % HID;
    const float* xr = xp + (size_t)b * (6 * HID);
    const float* wb = w1 + (size_t)half * (6 * HID) * HID + f;
    float acc = (half == 0) ? b1[f] : 0.f;
    #pragma unroll 4
    for (int k = 0; k < 6 * HID; k++) acc += xr[k] * wb[(size_t)k * HID];
    if (half == 0) U[(size_t)b * HID + f] = acc;
    else           V[(size_t)b * HID + f] = acc;
}

// ---------------------------------------------------------------- per pair-edge: out = tanh(U[a]+V[b]) . w2 + b2
__global__ __launch_bounds__(256) void k_edge(const int* __restrict__ pe, const float* __restrict__ U,
                                              const float* __restrict__ V, const float* __restrict__ w2,
                                              const float* __restrict__ b2, float* __restrict__ out, int EP) {
    int ep = blockIdx.x * blockDim.x + threadIdx.x;
    if (ep >= EP) return;
    int a = pe[ep];
    int b = pe[EP + ep];
    const float4* up = (const float4*)(U + (size_t)a * HID);
    const float4* vp = (const float4*)(V + (size_t)b * HID);
    float s = 0.f;
    #pragma unroll
    for (int q = 0; q < HID / 4; q++) {
        float4 u = up[q];
        float4 v = vp[q];
        s += tanh_fast(u.x + v.x) * w2[q * 4 + 0];
        s += tanh_fast(u.y + v.y) * w2[q * 4 + 1];
        s += tanh_fast(u.z + v.z) * w2[q * 4 + 2];
        s += tanh_fast(u.w + v.w) * w2[q * 4 + 3];
    }
    out[ep] = s + b2[0];
}

// ================================================================ host launch
extern "C" void kernel_launch(void* const* d_in, const int* in_sizes, int n_in,
                              void* d_out, int out_size, void* d_ws, size_t ws_size,
                              hipStream_t stream) {
    const float* x       = (const float*)d_in[0];
    const float* emb     = (const float*)d_in[1];
    const float* assign  = (const float*)d_in[2];
    const int*   ei      = (const int*)d_in[3];
    const int*   pe      = (const int*)d_in[4];
    const float* node_w  = (const float*)d_in[5];
    const float* node_b  = (const float*)d_in[6];
    const float* emb_w   = (const float*)d_in[7];
    const float* emb_b   = (const float*)d_in[8];
    const float* conv_wi = (const float*)d_in[9];
    const float* conv_wr = (const float*)d_in[10];
    const float* conv_b  = (const float*)d_in[11];
    const float* bn_g    = (const float*)d_in[12];
    const float* bn_b    = (const float*)d_in[13];
    const float* w1      = (const float*)d_in[14];
    const float* b1      = (const float*)d_in[15];
    const float* w2      = (const float*)d_in[16];
    const float* b2      = (const float*)d_in[17];

    int N = in_sizes[0] / 64;
    int B = in_sizes[2] / N;
    int E = in_sizes[3] / 2;
    int EP = in_sizes[4] / 2;
    float invN = 1.0f / (float)N;

    char* wp = (char*)d_ws;
    auto alloc = [&](size_t nbytes) -> void* {
        void* p = (void*)wp;
        wp += (nbytes + 255) & ~(size_t)255;
        return p;
    };
    float* t_buf  = (float*)alloc((size_t)N * HID * 4);
    float* t2     = (float*)alloc((size_t)N * HID * 4);
    float* hw     = (float*)alloc((size_t)N * HID * 4);
    float* e_buf  = (float*)alloc((size_t)N * HID * 4);
    int*   csr_r  = (int*)alloc((size_t)N * CAP * 4);
    int*   deg    = (int*)alloc((size_t)N * 4);
    int*   batchv = (int*)alloc((size_t)N * 4);
    int*   nlist  = (int*)alloc((size_t)N * 4);
    float* stats  = (float*)alloc((size_t)3 * 2 * HID * 4);
    int*   bcnt   = (int*)alloc((size_t)B * 4);
    int*   boffs  = (int*)alloc((size_t)B * 4);
    int*   bcur   = (int*)alloc((size_t)B * 4);
    float* xp     = (float*)alloc((size_t)B * 6 * HID * 4);
    float* Ub     = (float*)alloc((size_t)B * HID * 4);
    float* Vb     = (float*)alloc((size_t)B * HID * 4);

    const int* row = ei;
    const int* col = ei + E;

    int GD   = (N + 127) / 128;   // 128-node tiles (dense / conv halves)
    int GZ   = (N + 255) / 256;   // zero/bfill blocks
    int GG18 = (18 * N + 255) / 256;

    // D1: dense(x) + dense(emb) + zero-init
    k_d1<<<2 * GD + GZ, 256, 0, stream>>>(x, node_w, node_b, emb, emb_w, emb_b,
                                          t_buf, e_buf, deg, stats, bcnt, N, B, GD);

    // D2: CSR fill + conv0 (Wi->hw, Wr->t2) + argmax
    k_front2<<<GF + 2 * GD + GA, 256, 0, stream>>>(row, col, deg, csr_r, E,
                                                   t_buf, conv_wi, conv_wr, conv_b, hw, t2,
                                                   assign, batchv, bcnt, N, B, GD);

    // layer 0: gather (UNSCALED) + bucket scan; stats
    k_gather18<0><<<GG18 + 1, 256, 0, stream>>>(hw, deg, csr_r, t2, t_buf, N,
                                                B, bcnt, boffs, bcur);
    k_stats<<<288, 256, 0, stream>>>(t_buf, stats, N * HID / 4);

    // layer 1: split conv (BN from l0 stats, hw pre-scaled) + bfill role; gather; stats
    k_conv_s<<<2 * GD + GZ, 256, 0, stream>>>(t_buf, stats, bn_g, bn_b,
                                              conv_wi + (size_t)HID * HID, conv_wr + (size_t)HID * HID,
                                              conv_b + HID, hw, t2, deg, N, invN, GD,
                                              batchv, bcur, nlist);
    k_gather18<1><<<GG18, 256, 0, stream>>>(hw, deg, csr_r, t2, t_buf, N,
                                            0, nullptr, nullptr, nullptr);
    k_stats<<<288, 256, 0, stream>>>(t_buf, stats + 2 * HID, N * HID / 4);

    // layer 2: split conv (BN from l1 stats); gather; stats
    k_conv_s<<<2 * GD, 256, 0, stream>>>(t_buf, stats + 2 * HID, bn_g + HID, bn_b + HID,
                                         conv_wi + (size_t)2 * HID * HID, conv_wr + (size_t)2 * HID * HID,
                                         conv_b + 2 * HID, hw, t2, deg, N, invN, GD,
                                         nullptr, nullptr, nullptr);
    k_gather18<1><<<GG18, 256, 0, stream>>>(hw, deg, csr_r, t2, t_buf, N,
                                            0, nullptr, nullptr, nullptr);
    k_stats<<<288, 256, 0, stream>>>(t_buf, stats + 4 * HID, N * HID / 4);

    // pooling + MLP
    k_poolB<<<B, 576, 0, stream>>>(t_buf, e_buf, stats + 4 * HID,
                                   bn_g + 2 * HID, bn_b + 2 * HID,
                                   boffs, bcnt, nlist, xp, invN);
    k_uv<<<B, 192, 0, stream>>>(xp, w1, b1, Ub, Vb);
    k_edge<<<(EP + 255) / 256, 256, 0, stream>>>(pe, Ub, Vb, w2, b2, (float*)d_out, EP);
}